// Round 15
// baseline (304.662 us; speedup 1.0000x reference)
//
#include <hip/hip_runtime.h>
#include <hip/hip_bf16.h>
#include <math.h>

#define BB   4
#define LL   2048
#define INF_ 64
#define DD   256
#define NN   16
#define KK   32
#define BLn  (BB*LL)      // 8192
#define FCNT 1025
#define FSTR 1056
#define SKM  8192
#define SKN  256
#define PSZ  ((size_t)SKM * SKN)
#define IX(x) ((x) + ((x) >> 6))
#define SWZ(c, r) ((c) ^ (((r) & 3) << 3))

typedef short short4v __attribute__((ext_vector_type(4)));
typedef short short8 __attribute__((ext_vector_type(8)));
typedef float f32x4  __attribute__((ext_vector_type(4)));

__device__ __forceinline__ float softplusf(float x) {
    return x > 20.f ? x : log1pf(__expf(x));
}
__device__ __forceinline__ float sigmoidf_(float x) {
    return 1.f / (1.f + __expf(-x));
}
__device__ __forceinline__ short bfs(float v) {
    __hip_bfloat16 h = __float2bfloat16(v);
    return *reinterpret_cast<short*>(&h);
}
#define RAWBAR() do { asm volatile("s_waitcnt lgkmcnt(0)" ::: "memory"); \
                      __builtin_amdgcn_s_barrier(); } while (0)

// ============ fused prep: twiddle + all weight transpose/cast/pack ==========
__global__ void prep_kernel(const float* __restrict__ wd, const float* __restrict__ gw,
                            const float* __restrict__ pw, const float* __restrict__ wo,
                            const float* __restrict__ wb, const float* __restrict__ wc,
                            const float* __restrict__ w_in, float* __restrict__ tab,
                            __hip_bfloat16* __restrict__ cat0, __hip_bfloat16* __restrict__ cat1,
                            __hip_bfloat16* __restrict__ gwt, __hip_bfloat16* __restrict__ pwt,
                            __hip_bfloat16* __restrict__ wot, __hip_bfloat16* __restrict__ wint) {
    __shared__ float t[32][33];
    const int tid = threadIdx.x;
    int blk = blockIdx.x;
    if (blk < 8) {
        int i = blk * 256 + tid;
        if (i < 2048) {
            double ang = 2.0 * 3.14159265358979323846 * (double)i / 2048.0;
            tab[i]        = (float)cos(ang);
            tab[2048 + i] = (float)sin(ang);
        }
        return;
    }
    blk -= 8;
    const float* W; __hip_bfloat16* Wt; int K, N, bx, by;
    if (blk < 64)        { W = wd;                     Wt = cat0; K = 256;  N = 256; bx = blk & 7; by = blk >> 3; }
    else if (blk < 128)  { int q = blk - 64;  W = wd + 65536; Wt = cat1; K = 256; N = 256; bx = q & 7; by = q >> 3; }
    else if (blk < 192)  { int q = blk - 128; W = gw;  Wt = gwt;  K = 256;  N = 256; bx = q & 7; by = q >> 3; }
    else if (blk < 256)  { int q = blk - 192; W = pw;  Wt = pwt;  K = 256;  N = 256; bx = q & 7; by = q >> 3; }
    else if (blk < 1280) { int q = blk - 256; W = wo;  Wt = wot;  K = 4096; N = 256; bx = q & 7; by = q >> 3; }
    else if (blk < 1344) {
        int j = (blk - 1280) & 31;
        const float* src0 = (blk < 1312) ? wb : wb + DD * NN;
        const float* src1 = (blk < 1312) ? wc : wc + DD * NN;
        __hip_bfloat16* cat = (blk < 1312) ? cat0 : cat1;
        const float* src = (j < 16) ? src0 : src1;
        cat[(size_t)(256 + j) * 256 + tid] = __float2bfloat16(src[tid * 16 + (j & 15)]);
        return;
    } else { int q = blk - 1344; W = w_in; Wt = wint; K = 64; N = 256; bx = q & 7; by = q >> 3; }
    const int k0 = by * 32, n0 = bx * 32;
    if (k0 >= K) return;
    const int tx = tid & 31, ty = tid >> 5;
    for (int r = ty; r < 32; r += 8) t[r][tx] = W[(size_t)(k0 + r) * N + n0 + tx];
    __syncthreads();
    for (int r = ty; r < 32; r += 8)
        Wt[(size_t)(n0 + r) * K + k0 + tx] = __float2bfloat16(t[tx][r]);
}

// ============ input proj: h = x@w_in + b_in (MFMA), also writes ht ==========
__global__ __launch_bounds__(256)
void gemm_in_kernel(const float* __restrict__ x, const __hip_bfloat16* __restrict__ wint,
                    const float* __restrict__ b_in, float* __restrict__ h,
                    float* __restrict__ ht) {
    __shared__ alignas(16) short As[64][72];
    __shared__ alignas(16) short Bs[64][72];
    __shared__ float ts[64][68];
    const int tid = threadIdx.x;
    const int w = tid >> 6, lane = tid & 63;
    const int hi = lane >> 4, lo = lane & 15;
    const int row0 = blockIdx.y * 64, col0 = blockIdx.x * 64;
    const short* B = (const short*)wint;
#pragma unroll
    for (int e = 0; e < 4; ++e) {
        int q = e * 256 + tid;
        int r = q >> 4, c4 = (q & 15) * 4;
        float4 v = *(const float4*)&x[(size_t)(row0 + r) * 64 + c4];
        short4v s = {bfs(v.x), bfs(v.y), bfs(v.z), bfs(v.w)};
        *(short4v*)&As[r][c4] = s;
    }
#pragma unroll
    for (int e = 0; e < 2; ++e) {
        int q = e * 256 + tid;
        int r = q >> 3, c8 = (q & 7) * 8;
        *(short8*)&Bs[r][c8] = *(const short8*)&B[(size_t)(col0 + r) * 64 + c8];
    }
    __syncthreads();
    f32x4 acc[4];
    f32x4 zz = {0.f, 0.f, 0.f, 0.f};
#pragma unroll
    for (int n = 0; n < 4; ++n) acc[n] = zz;
#pragma unroll
    for (int s = 0; s < 2; ++s) {
        short8 af = *(const short8*)&As[w * 16 + lo][s * 32 + hi * 8];
#pragma unroll
        for (int n = 0; n < 4; ++n) {
            short8 bf = *(const short8*)&Bs[n * 16 + lo][s * 32 + hi * 8];
            acc[n] = __builtin_amdgcn_mfma_f32_16x16x32_bf16(af, bf, acc[n], 0, 0, 0);
        }
    }
#pragma unroll
    for (int n = 0; n < 4; ++n)
#pragma unroll
        for (int r = 0; r < 4; ++r) {
            const int row = row0 + w * 16 + hi * 4 + r;
            const int col = col0 + n * 16 + lo;
            float v = acc[n][r] + b_in[col];
            h[(size_t)row * 256 + col] = v;
            ts[n * 16 + lo][w * 16 + hi * 4 + r] = v;
        }
    __syncthreads();
    const int b = row0 >> 11, l0 = row0 & 2047, d0 = col0;
    const int dr = tid >> 2, seg = tid & 3;
    float* dst = ht + ((size_t)(b * 256 + d0 + dr)) * LL + l0 + seg * 16;
#pragma unroll
    for (int j = 0; j < 4; ++j)
        *(f32x4*)&dst[j * 4] = *(const f32x4*)&ts[dr][seg * 16 + j * 4];
}

// ============ fused LayerNorm + depthwise conv (32 rows/block) ==============
__global__ __launch_bounds__(256)
void lnconv_kernel(const float* __restrict__ X, const float* __restrict__ g,
                   const float* __restrict__ bln, const float* __restrict__ cw,
                   const float* __restrict__ cb, __hip_bfloat16* __restrict__ xn_bf,
                   __hip_bfloat16* __restrict__ xc_bf) {
    __shared__ float xs[34][260];
    const int tid = threadIdx.x;
    const int w = tid >> 6, lane = tid & 63;
    const int blk = blockIdx.x;
    const int b = (blk * 32) >> 11, L0 = (blk * 32) & 2047;
    const float4 g4 = *(const float4*)&g[lane * 4];
    const float4 b4 = *(const float4*)&bln[lane * 4];
    for (int slot = w; slot < 34; slot += 4) {
        const int l = L0 - 1 + slot;
        if (l < 0 || l >= LL) {
            f32x4 z = {0.f, 0.f, 0.f, 0.f};
            *(f32x4*)&xs[slot][lane * 4] = z;
            continue;
        }
        float4 v = *(const float4*)&X[((size_t)b * LL + l) * DD + lane * 4];
        float s = v.x + v.y + v.z + v.w;
#pragma unroll
        for (int off = 1; off < 64; off <<= 1) s += __shfl_xor(s, off);
        float m = s * (1.f / DD);
        float cx = v.x - m, cy = v.y - m, cz = v.z - m, cw_ = v.w - m;
        float q = cx * cx + cy * cy + cz * cz + cw_ * cw_;
#pragma unroll
        for (int off = 1; off < 64; off <<= 1) q += __shfl_xor(q, off);
        float inv = rsqrtf(q * (1.f / DD) + 1e-5f);
        f32x4 y;
        y[0] = cx * inv * g4.x + b4.x;
        y[1] = cy * inv * g4.y + b4.y;
        y[2] = cz * inv * g4.z + b4.z;
        y[3] = cw_ * inv * g4.w + b4.w;
        *(f32x4*)&xs[slot][lane * 4] = y;
        if (slot >= 1 && slot <= 32) {
            short4v s4 = {bfs(y[0]), bfs(y[1]), bfs(y[2]), bfs(y[3])};
            *(short4v*)&xn_bf[((size_t)b * LL + l) * DD + lane * 4] = s4;
        }
    }
    __syncthreads();
    const int d = tid;
    const float w0 = cw[d * 3 + 0], w1 = cw[d * 3 + 1], w2 = cw[d * 3 + 2], cbd = cb[d];
    float xm = xs[0][d], x0 = xs[1][d];
    for (int rw = 0; rw < 32; ++rw) {
        float xp = xs[rw + 2][d];
        xc_bf[((size_t)b * LL + L0 + rw) * DD + d] =
            __float2bfloat16(fmaf(w0, xm, fmaf(w1, x0, fmaf(w2, xp, cbd))));
        xm = x0; x0 = xp;
    }
}

// ============ 64x64 MFMA core, K=256, depth-2 pipeline, swizzled LDS ========
template<int MODE>
__global__ __launch_bounds__(256)
void gemm_core(const short* __restrict__ A, const short* __restrict__ Bw,
               const float* __restrict__ bias, const float* __restrict__ x1,
               const float* __restrict__ x2, float* __restrict__ o0,
               float* __restrict__ o1, float* __restrict__ o2,
               __hip_bfloat16* __restrict__ ob) {
    __shared__ alignas(16) short As[2][64][40];
    __shared__ alignas(16) short Bs[2][64][40];
    const int tid = threadIdx.x;
    const int w = tid >> 6, lane = tid & 63;
    const int hi = lane >> 4, lo = lane & 15;
    const int row0 = blockIdx.y * 64, col0 = blockIdx.x * 64;
    f32x4 acc[4];
    f32x4 zz = {0.f, 0.f, 0.f, 0.f};
#pragma unroll
    for (int n = 0; n < 4; ++n) acc[n] = zz;
    const int sr = tid >> 2, scw = SWZ((tid & 3) * 8, tid >> 2);
    const size_t aoff = (size_t)(row0 + sr) * 256 + (tid & 3) * 8;
    const size_t boff = (size_t)(col0 + sr) * 256 + (tid & 3) * 8;
    const int rcol = SWZ(hi * 8, lo);
    short8 a_s0, b_s0, a_s1, b_s1;
#define GC_LOAD0(t) { a_s0 = *(const short8*)&A[aoff + (t) * 32]; \
                      b_s0 = *(const short8*)&Bw[boff + (t) * 32]; }
#define GC_LOAD1(t) { a_s1 = *(const short8*)&A[aoff + (t) * 32]; \
                      b_s1 = *(const short8*)&Bw[boff + (t) * 32]; }
#define GC_WRITE0(buf) { *(short8*)&As[buf][sr][scw] = a_s0; *(short8*)&Bs[buf][sr][scw] = b_s0; }
#define GC_WRITE1(buf) { *(short8*)&As[buf][sr][scw] = a_s1; *(short8*)&Bs[buf][sr][scw] = b_s1; }
#define GC_COMPUTE(buf) { \
        short8 af = *(const short8*)&As[buf][w * 16 + lo][rcol]; \
        short8 bf0 = *(const short8*)&Bs[buf][0 * 16 + lo][rcol]; \
        short8 bf1 = *(const short8*)&Bs[buf][1 * 16 + lo][rcol]; \
        short8 bf2 = *(const short8*)&Bs[buf][2 * 16 + lo][rcol]; \
        short8 bf3 = *(const short8*)&Bs[buf][3 * 16 + lo][rcol]; \
        acc[0] = __builtin_amdgcn_mfma_f32_16x16x32_bf16(af, bf0, acc[0], 0, 0, 0); \
        acc[1] = __builtin_amdgcn_mfma_f32_16x16x32_bf16(af, bf1, acc[1], 0, 0, 0); \
        acc[2] = __builtin_amdgcn_mfma_f32_16x16x32_bf16(af, bf2, acc[2], 0, 0, 0); \
        acc[3] = __builtin_amdgcn_mfma_f32_16x16x32_bf16(af, bf3, acc[3], 0, 0, 0); }
    GC_LOAD0(0); GC_LOAD1(1);
    GC_WRITE0(0);
    RAWBAR();
#pragma unroll
    for (int j = 0; j < 8; j += 2) {
        if (j + 2 < 8) GC_LOAD0(j + 2);
        GC_WRITE1(1);
        GC_COMPUTE(0);
        RAWBAR();
        if (j + 3 < 8) GC_LOAD1(j + 3);
        if (j + 2 < 8) GC_WRITE0(0);
        GC_COMPUTE(1);
        RAWBAR();
    }
#pragma unroll
    for (int n = 0; n < 4; ++n) {
#pragma unroll
        for (int r = 0; r < 4; ++r) {
            const int row = row0 + w * 16 + hi * 4 + r;
            const int col = col0 + n * 16 + lo;
            float v = acc[n][r];
            if constexpr (MODE == 0) {
                if (col < 256)      o0[(size_t)row * 256 + col] = softplusf(v + bias[col]);
                else if (col < 272) o1[(size_t)row * 16 + col - 256] = v;
                else if (col < 288) o2[(size_t)row * 16 + col - 272] = v;
            } else if constexpr (MODE == 1) {
                float gv = sigmoidf_(v + bias[col]);
                size_t idx = (size_t)row * 256 + col;
                float s = x1[idx] + x1[PSZ + idx] + x1[2 * PSZ + idx] + x1[3 * PSZ + idx] + x2[col];
                ob[idx] = __float2bfloat16(gv * s);
            } else {
                o0[(size_t)row * 256 + col] = v + bias[col] + x1[(size_t)row * 256 + col];
            }
        }
    }
}

// ============ split-K GEMM ys@wo: NO LDS, 64x64 wave tiles, KSPLIT=4 ========
// Each wave owns a 64x64 output tile; A and B fragments load global->register
// directly (A is never inter-wave shared; B slab is L2-resident). No barriers.
__global__ __launch_bounds__(256)
void gemm_sk_kernel(const __hip_bfloat16* __restrict__ Abf, const __hip_bfloat16* __restrict__ Wt,
                    float* __restrict__ P) {
    const int tid = threadIdx.x;
    const int f = blockIdx.x;                   // 0..511
    const int xcd = f & 7, s = f >> 3;          // s 0..63
    const int col = s & 3, u = s >> 2;          // u 0..15
    const int rowkb = xcd + u * 8;              // 0..127 bijective
    const int rowslab = rowkb & 31, kb = rowkb >> 5;   // kb 0..3 (K=1024 each)
    const int w = tid >> 6, lane = tid & 63;
    const int hi = lane >> 4, lo = lane & 15;
    const int wrow = rowslab * 256 + w * 64;    // this wave's 64 rows
    const int col0 = col * 64;
    const size_t kbase = (size_t)kb * 1024;
    const short* A = (const short*)Abf;
    const short* B = (const short*)Wt;
    f32x4 acc[4][4];
    f32x4 zz = {0.f, 0.f, 0.f, 0.f};
#pragma unroll
    for (int m = 0; m < 4; ++m)
#pragma unroll
        for (int n = 0; n < 4; ++n) acc[m][n] = zz;
    const size_t ao0 = (size_t)(wrow + 0 * 16 + lo) * 4096 + kbase + hi * 8;
    const size_t ao1 = (size_t)(wrow + 1 * 16 + lo) * 4096 + kbase + hi * 8;
    const size_t ao2 = (size_t)(wrow + 2 * 16 + lo) * 4096 + kbase + hi * 8;
    const size_t ao3 = (size_t)(wrow + 3 * 16 + lo) * 4096 + kbase + hi * 8;
    const size_t bo0 = (size_t)(col0 + 0 * 16 + lo) * 4096 + kbase + hi * 8;
    const size_t bo1 = (size_t)(col0 + 1 * 16 + lo) * 4096 + kbase + hi * 8;
    const size_t bo2 = (size_t)(col0 + 2 * 16 + lo) * 4096 + kbase + hi * 8;
    const size_t bo3 = (size_t)(col0 + 3 * 16 + lo) * 4096 + kbase + hi * 8;
    short8 aX0, aX1, aX2, aX3, bX0, bX1, bX2, bX3;   // slot X
    short8 aY0, aY1, aY2, aY3, bY0, bY1, bY2, bY3;   // slot Y
#define SK_LOADX(t) { size_t ko = (size_t)(t) * 32; \
        aX0 = *(const short8*)&A[ao0 + ko]; aX1 = *(const short8*)&A[ao1 + ko]; \
        aX2 = *(const short8*)&A[ao2 + ko]; aX3 = *(const short8*)&A[ao3 + ko]; \
        bX0 = *(const short8*)&B[bo0 + ko]; bX1 = *(const short8*)&B[bo1 + ko]; \
        bX2 = *(const short8*)&B[bo2 + ko]; bX3 = *(const short8*)&B[bo3 + ko]; }
#define SK_LOADY(t) { size_t ko = (size_t)(t) * 32; \
        aY0 = *(const short8*)&A[ao0 + ko]; aY1 = *(const short8*)&A[ao1 + ko]; \
        aY2 = *(const short8*)&A[ao2 + ko]; aY3 = *(const short8*)&A[ao3 + ko]; \
        bY0 = *(const short8*)&B[bo0 + ko]; bY1 = *(const short8*)&B[bo1 + ko]; \
        bY2 = *(const short8*)&B[bo2 + ko]; bY3 = *(const short8*)&B[bo3 + ko]; }
#define MF(a_, b_, c_) __builtin_amdgcn_mfma_f32_16x16x32_bf16(a_, b_, c_, 0, 0, 0)
#define SK_COMPX() { \
        acc[0][0]=MF(aX0,bX0,acc[0][0]); acc[0][1]=MF(aX0,bX1,acc[0][1]); \
        acc[0][2]=MF(aX0,bX2,acc[0][2]); acc[0][3]=MF(aX0,bX3,acc[0][3]); \
        acc[1][0]=MF(aX1,bX0,acc[1][0]); acc[1][1]=MF(aX1,bX1,acc[1][1]); \
        acc[1][2]=MF(aX1,bX2,acc[1][2]); acc[1][3]=MF(aX1,bX3,acc[1][3]); \
        acc[2][0]=MF(aX2,bX0,acc[2][0]); acc[2][1]=MF(aX2,bX1,acc[2][1]); \
        acc[2][2]=MF(aX2,bX2,acc[2][2]); acc[2][3]=MF(aX2,bX3,acc[2][3]); \
        acc[3][0]=MF(aX3,bX0,acc[3][0]); acc[3][1]=MF(aX3,bX1,acc[3][1]); \
        acc[3][2]=MF(aX3,bX2,acc[3][2]); acc[3][3]=MF(aX3,bX3,acc[3][3]); }
#define SK_COMPY() { \
        acc[0][0]=MF(aY0,bY0,acc[0][0]); acc[0][1]=MF(aY0,bY1,acc[0][1]); \
        acc[0][2]=MF(aY0,bY2,acc[0][2]); acc[0][3]=MF(aY0,bY3,acc[0][3]); \
        acc[1][0]=MF(aY1,bY0,acc[1][0]); acc[1][1]=MF(aY1,bY1,acc[1][1]); \
        acc[1][2]=MF(aY1,bY2,acc[1][2]); acc[1][3]=MF(aY1,bY3,acc[1][3]); \
        acc[2][0]=MF(aY2,bY0,acc[2][0]); acc[2][1]=MF(aY2,bY1,acc[2][1]); \
        acc[2][2]=MF(aY2,bY2,acc[2][2]); acc[2][3]=MF(aY2,bY3,acc[2][3]); \
        acc[3][0]=MF(aY3,bY0,acc[3][0]); acc[3][1]=MF(aY3,bY1,acc[3][1]); \
        acc[3][2]=MF(aY3,bY2,acc[3][2]); acc[3][3]=MF(aY3,bY3,acc[3][3]); }
    SK_LOADX(0);
    SK_LOADY(1);
    for (int j = 0; j < 32; j += 2) {
        SK_COMPX();
        if (j + 2 < 32) SK_LOADX(j + 2);
        SK_COMPY();
        if (j + 3 < 32) SK_LOADY(j + 3);
    }
    float* Pk = P + (size_t)kb * PSZ;
#pragma unroll
    for (int m = 0; m < 4; ++m)
#pragma unroll
        for (int n = 0; n < 4; ++n)
#pragma unroll
            for (int r = 0; r < 4; ++r) {
                int rr = wrow + m * 16 + hi * 4 + r;
                int cc = col0 + n * 16 + lo;
                Pk[(size_t)rr * SKN + cc] = acc[m][n][r];
            }
}

// ============ chunked SSM scan (PHASE 1 computes its own hstart) ============
template<int PHASE>
__global__ void ssm_chunk_kernel(const float* __restrict__ delta, const float* __restrict__ Bt,
                                 const float* __restrict__ Ct, const float* __restrict__ loglam,
                                 float* __restrict__ sA, float* __restrict__ sB,
                                 __hip_bfloat16* __restrict__ ys) {
    __shared__ float dl[128][16];
    __shared__ float btl[128][16];
    __shared__ float ctl[128][16];
    const int dblk = blockIdx.x, c = blockIdx.y, b = blockIdx.z;
    const int tid = threadIdx.x;
    const size_t lbase = (size_t)b * LL + c * 128;
    for (int i = tid; i < 2048; i += 256) {
        int l = i >> 4, q = i & 15;
        dl[l][q]  = delta[(lbase + l) * DD + dblk * 16 + q];
        btl[l][q] = Bt[(lbase + l) * NN + q];
        if (PHASE == 1) ctl[l][q] = Ct[(lbase + l) * NN + q];
    }
    float hv = 0.f, ap = 1.f;
    if (PHASE == 1) {
        for (int cc = 0; cc < c; ++cc) {
            size_t oi = ((size_t)(b * 16 + cc)) * 4096 + dblk * 256 + tid;
            hv = fmaf(sA[oi], hv, sB[oi]);
        }
    }
    __syncthreads();
    const int dloc = tid >> 4, n = tid & 15;
    const float lam = softplusf(loglam[(dblk * 16 + dloc) * NN + n]);
    for (int l = 0; l < 128; ++l) {
        float dv = dl[l][dloc];
        float a = __expf(-dv * lam);
        hv = fmaf(a, hv, dv * btl[l][n]);
        if (PHASE == 0) ap *= a;
        else ys[(lbase + l) * (DD * NN) + dblk * 256 + tid] = __float2bfloat16(hv * ctl[l][n]);
    }
    if (PHASE == 0) {
        size_t oi = ((size_t)(b * 16 + c)) * 4096 + dblk * 256 + tid;
        sA[oi] = ap; sB[oi] = hv;
    }
}

// ============ layer-2 last-position: chain hfin in-kernel, split-K part ====
__global__ void last_ssm_part_kernel(const float* __restrict__ sA, const float* __restrict__ sB,
                                     const float* __restrict__ Ct,
                                     const float* __restrict__ wo, float* __restrict__ part) {
    __shared__ float hC[4][128];
    const int c = blockIdx.x, tid = threadIdx.x;
    const int p0 = c * 128;
#pragma unroll
    for (int e = 0; e < 2; ++e) {
        int i = e * 256 + tid;
        int b = i >> 7, p = i & 127;
        float hh = 0.f;
#pragma unroll
        for (int cc = 0; cc < 16; ++cc) {
            size_t oi = ((size_t)(b * 16 + cc)) * 4096 + p0 + p;
            hh = fmaf(sA[oi], hh, sB[oi]);
        }
        hC[b][p] = hh * Ct[((size_t)b * LL + (LL - 1)) * NN + (p & 15)];
    }
    __syncthreads();
    float a0 = 0.f, a1 = 0.f, a2 = 0.f, a3 = 0.f;
    for (int p = 0; p < 128; ++p) {
        float wv = wo[(size_t)(p0 + p) * DD + tid];
        a0 = fmaf(hC[0][p], wv, a0);
        a1 = fmaf(hC[1][p], wv, a1);
        a2 = fmaf(hC[2][p], wv, a2);
        a3 = fmaf(hC[3][p], wv, a3);
    }
    part[(0 * 32 + c) * DD + tid] = a0;
    part[(1 * 32 + c) * DD + tid] = a1;
    part[(2 * 32 + c) * DD + tid] = a2;
    part[(3 * 32 + c) * DD + tid] = a3;
}

__global__ void last_redproj_kernel(const float* __restrict__ part, const float* __restrict__ bo,
                                    const __hip_bfloat16* __restrict__ xn, const float* __restrict__ gw,
                                    const float* __restrict__ gb, const float* __restrict__ pw,
                                    const float* __restrict__ pb, const float* __restrict__ resid,
                                    float* __restrict__ xtlast) {
    __shared__ float xrow[256];
    __shared__ float xsg[256];
    const int b = blockIdx.x, d = threadIdx.x;
    float ol = bo[d];
#pragma unroll
    for (int c = 0; c < 32; ++c) ol += part[(b * 32 + c) * DD + d];
    const size_t rbase = ((size_t)b * LL + (LL - 1)) * DD;
    xrow[d] = __bfloat162float(xn[rbase + d]);
    __syncthreads();
    float acc = gb[d];
    for (int k = 0; k < 256; ++k) acc = fmaf(xrow[k], gw[(size_t)k * DD + d], acc);
    xsg[d] = ol * sigmoidf_(acc);
    __syncthreads();
    float acc2 = pb[d];
    for (int k = 0; k < 256; ++k) acc2 = fmaf(xsg[k], pw[(size_t)k * DD + d], acc2);
    xtlast[b * DD + d] = acc2 + resid[rbase + d];
}

// ============ packed radix-2 FFT: 2 real seqs per block =====================
__global__ __launch_bounds__(256)
void fft2_kernel(const float* __restrict__ ht, const float* __restrict__ tab,
                 float* __restrict__ Xre, float* __restrict__ Xim) {
    __shared__ float re[2080];
    __shared__ float im[2080];
    __shared__ float c2[2048];
    __shared__ float s2[2048];
    const int tid = threadIdx.x;
    const int pair = blockIdx.x;
    const int b = pair >> 7, d0 = pair & 127;
    for (int p = tid; p < 2048; p += 256) {
        if (p >= 1) {
            int lh = 31 - __clz((unsigned)p);
            int j = p - (1 << lh);
            int t = j << (10 - lh);
            c2[p] = tab[t]; s2[p] = tab[2048 + t];
        }
    }
    const float* ha = ht + ((size_t)b * 256 + d0) * LL;
    const float* hb = ha + (size_t)128 * LL;
    for (int i = tid; i < 2048; i += 256) {
        int r = (int)(__brev((unsigned)i) >> 21);
        re[IX(r)] = ha[i];
        im[IX(r)] = hb[i];
    }
    __syncthreads();
#pragma unroll
    for (int s = 1; s <= 11; ++s) {
        const int half = 1 << (s - 1);
#pragma unroll
        for (int e = 0; e < 4; ++e) {
            int q = e * 256 + tid;
            int j = q & (half - 1);
            int i0 = ((q >> (s - 1)) << s) + j;
            int i1 = i0 + half;
            float wr = c2[half + j], wi = -s2[half + j];
            float xr = re[IX(i1)], xi = im[IX(i1)];
            float tr = xr * wr - xi * wi;
            float ti = xr * wi + xi * wr;
            float ur = re[IX(i0)], ui = im[IX(i0)];
            re[IX(i0)] = ur + tr; im[IX(i0)] = ui + ti;
            re[IX(i1)] = ur - tr; im[IX(i1)] = ui - ti;
        }
        __syncthreads();
    }
    const int seqa = b * 256 + d0;
    float* xra = Xre + (size_t)seqa * FSTR;
    float* xia = Xim + (size_t)seqa * FSTR;
    float* xrb = xra + (size_t)128 * FSTR;
    float* xib = xia + (size_t)128 * FSTR;
    for (int f = tid; f < FCNT; f += 256) {
        int nf = (2048 - f) & 2047;
        float zrf = re[IX(f)], zif = im[IX(f)];
        float zrn = re[IX(nf)], zin = im[IX(nf)];
        xra[f] = 0.5f * (zrf + zrn);
        xia[f] = 0.5f * (zif - zin);
        xrb[f] = 0.5f * (zif + zin);
        xib[f] = 0.5f * (zrn - zrf);
    }
}

// ============ mag partials / topk / fused xslast+head =======================
__global__ void mag_part_kernel(const float* __restrict__ Xre, const float* __restrict__ Xim,
                                float* __restrict__ part) {
    const int fb = blockIdx.x, sb = blockIdx.y;
    const int tid = threadIdx.x;
    const int f = fb * 256 + tid;
    float s = 0.f;
    if (f < FCNT) {
        for (int q = 0; q < 64; ++q) {
            size_t base = (size_t)(sb * 64 + q) * FSTR + f;
            float re = Xre[base], im = Xim[base];
            s += sqrtf(re * re + im * im);
        }
    }
    part[sb * 1280 + fb * 256 + tid] = s;
}

// top-32: 4 waves each do top-32 of a contiguous 320-slice, thread0 merges.
__global__ void topk_kernel(const float* __restrict__ part, int* __restrict__ sel) {
    __shared__ float vals[1280];
    __shared__ float wval[4][32];
    __shared__ int   widx[4][32];
    const int tid = threadIdx.x;
    const int lane = tid & 63, wid = tid >> 6;
    for (int i = tid; i < 1280; i += 256) {
        float v = -1e30f;
        if (i < FCNT) {
            v = 0.f;
#pragma unroll
            for (int sb = 0; sb < 16; ++sb) v += part[sb * 1280 + i];
        }
        vals[i] = v;
    }
    __syncthreads();
    const int base = wid * 320;
    for (int k = 0; k < 32; ++k) {
        float bv = -1e30f; int bi = 0x7fffffff;
#pragma unroll
        for (int q = 0; q < 5; ++q) {
            int i = base + q * 64 + lane;
            float v = vals[i];
            if (v > bv) { bv = v; bi = i; }
        }
#pragma unroll
        for (int off = 32; off > 0; off >>= 1) {
            float ov = __shfl_down(bv, off);
            int   oi = __shfl_down(bi, off);
            if (ov > bv || (ov == bv && oi < bi)) { bv = ov; bi = oi; }
        }
        bv = __shfl(bv, 0);
        bi = __shfl(bi, 0);
        if (lane == 0) { wval[wid][k] = bv; widx[wid][k] = bi; }
        vals[bi] = -1e30f;
    }
    __syncthreads();
    if (tid == 0) {
        int p0 = 0, p1 = 0, p2 = 0, p3 = 0;
        for (int k = 0; k < 32; ++k) {
            float v0 = wval[0][p0], v1 = wval[1][p1], v2 = wval[2][p2], v3 = wval[3][p3];
            int bw = 0; float bv = v0;
            if (v1 > bv) { bv = v1; bw = 1; }
            if (v2 > bv) { bv = v2; bw = 2; }
            if (v3 > bv) { bv = v3; bw = 3; }
            if (bw == 0)      { sel[k] = widx[0][p0++]; }
            else if (bw == 1) { sel[k] = widx[1][p1++]; }
            else if (bw == 2) { sel[k] = widx[2][p2++]; }
            else              { sel[k] = widx[3][p3++]; }
        }
    }
}

// fused: per-(b,d) spectral reconstruction at t=L-1, then mix/LN/MLP head
__global__ void head_kernel(const float* __restrict__ Xre, const float* __restrict__ Xim,
                            const int* __restrict__ sel, const float* __restrict__ fr,
                            const float* __restrict__ fi, const float* __restrict__ tab,
                            const float* __restrict__ xtlast,
                            const float* __restrict__ alpha, const float* __restrict__ beta,
                            const float* __restrict__ gout, const float* __restrict__ bout,
                            const float* __restrict__ hw1, const float* __restrict__ hb1,
                            const float* __restrict__ hw2, const float* __restrict__ hb2,
                            float* __restrict__ out) {
    __shared__ float red[256];
    __shared__ float z[256];
    __shared__ float hid[128];
    const int b = blockIdx.x, tid = threadIdx.x;
    const size_t sbase = (size_t)(b * 256 + tid) * FSTR;
    float xsl = 0.f;
    for (int j = 0; j < 32; ++j) {
        int f = sel[j];
        float xr = Xre[sbase + f];
        float xi = Xim[sbase + f];
        float frv = fr[tid * KK + j], fiv = fi[tid * KK + j];
        float xor_ = xr * frv - xi * fiv;
        float xoi  = xr * fiv + xi * frv;
        int kk2 = (f * (LL - 1)) & (LL - 1);
        float c = tab[kk2], s = tab[2048 + kk2];
        float w = (f == 0 || f == 1024) ? 1.f : 2.f;
        xsl = fmaf(w, xor_ * c - xoi * s, xsl);
    }
    xsl *= (1.f / LL);
    float zv = alpha[tid] * xtlast[b * 256 + tid] + beta[tid] * xsl;
    red[tid] = zv; __syncthreads();
    for (int s = 128; s > 0; s >>= 1) { if (tid < s) red[tid] += red[tid + s]; __syncthreads(); }
    float m = red[0] * (1.f / DD);
    __syncthreads();
    float c = zv - m;
    red[tid] = c * c; __syncthreads();
    for (int s = 128; s > 0; s >>= 1) { if (tid < s) red[tid] += red[tid + s]; __syncthreads(); }
    float var = red[0] * (1.f / DD);
    z[tid] = c * rsqrtf(var + 1e-5f) * gout[tid] + bout[tid];
    __syncthreads();
    if (tid < 128) {
        float a = hb1[tid];
        for (int k = 0; k < 256; ++k) a = fmaf(z[k], hw1[(size_t)k * 128 + tid], a);
        hid[tid] = a * sigmoidf_(a);
    }
    __syncthreads();
    if (tid < 2) {
        float a = hb2[tid];
        for (int k = 0; k < 128; ++k) a = fmaf(hid[k], hw2[(size_t)k * 2 + tid], a);
        out[b * 2 + tid] = a;
    }
}

extern "C" void kernel_launch(void* const* d_in, const int* in_sizes, int n_in,
                              void* d_out, int out_size, void* d_ws, size_t ws_size,
                              hipStream_t stream) {
    const float* x      = (const float*)d_in[0];
    const float* w_in   = (const float*)d_in[1];
    const float* b_in   = (const float*)d_in[2];
    const float* ln_g   = (const float*)d_in[3];
    const float* ln_b   = (const float*)d_in[4];
    const float* conv_w = (const float*)d_in[5];
    const float* conv_b = (const float*)d_in[6];
    const float* loglam = (const float*)d_in[7];
    const float* wd     = (const float*)d_in[8];
    const float* bd     = (const float*)d_in[9];
    const float* wb     = (const float*)d_in[10];
    const float* wc     = (const float*)d_in[11];
    const float* wo     = (const float*)d_in[12];
    const float* bo     = (const float*)d_in[13];
    const float* gw     = (const float*)d_in[14];
    const float* gb     = (const float*)d_in[15];
    const float* pw     = (const float*)d_in[16];
    const float* pb     = (const float*)d_in[17];
    const float* fr     = (const float*)d_in[18];
    const float* fi     = (const float*)d_in[19];
    const float* alpha  = (const float*)d_in[20];
    const float* beta   = (const float*)d_in[21];
    const float* gout   = (const float*)d_in[22];
    const float* bout   = (const float*)d_in[23];
    const float* hw1    = (const float*)d_in[24];
    const float* hb1    = (const float*)d_in[25];
    const float* hw2    = (const float*)d_in[26];
    const float* hb2    = (const float*)d_in[27];

    float* ws = (float*)d_ws;
    size_t o = 0;
    auto alloc = [&](size_t n) { float* p = ws + o; o += (n + 15) & ~(size_t)15; return p; };

    const size_t BLnDD = (size_t)BLn * DD;
    float* h      = alloc(BLnDD);
    float* xt1    = alloc(BLnDD);
    float* ht     = alloc(BLnDD);
    float* delta  = alloc(BLnDD);
    float* Pbuf   = alloc(4 * PSZ);                 // split-K partials (32 MB)
    float* Btm    = alloc((size_t)BLn * NN);
    float* Ctm    = alloc((size_t)BLn * NN);
    float* tab    = alloc(4096);
    float* ysf    = alloc(BLnDD * NN / 2);          // ys bf16; later Xre/Xim
    float* sA     = alloc((size_t)BB * 16 * 4096);
    float* sB     = alloc((size_t)BB * 16 * 4096);
    float* xnbf_f = alloc(BLnDD / 2);
    float* xcbf_f = alloc(BLnDD / 2);
    float* xsgf   = alloc(BLnDD / 2);
    float* cat0_f = alloc((size_t)320 * 256 / 2);
    float* cat1_f = alloc((size_t)320 * 256 / 2);
    float* gwt_f  = alloc((size_t)DD * DD / 2);
    float* pwt_f  = alloc((size_t)DD * DD / 2);
    float* wot_f  = alloc((size_t)DD * NN * DD / 2);
    float* wint_f = alloc((size_t)DD * 64 / 2);
    float* magp   = alloc(16 * 1280);
    int*   sel    = (int*)alloc(32);
    float* lpart  = alloc((size_t)BB * 32 * DD);
    float* xtlast = alloc(BB * DD);

    __hip_bfloat16* ys    = (__hip_bfloat16*)ysf;
    float*          Xre   = ysf;
    float*          Xim   = ysf + (size_t)1024 * FSTR;
    __hip_bfloat16* xn_bf = (__hip_bfloat16*)xnbf_f;
    __hip_bfloat16* xc_bf = (__hip_bfloat16*)xcbf_f;
    __hip_bfloat16* xsg_bf= (__hip_bfloat16*)xsgf;
    __hip_bfloat16* cat0  = (__hip_bfloat16*)cat0_f;
    __hip_bfloat16* cat1  = (__hip_bfloat16*)cat1_f;
    __hip_bfloat16* gwt   = (__hip_bfloat16*)gwt_f;
    __hip_bfloat16* pwt   = (__hip_bfloat16*)pwt_f;
    __hip_bfloat16* wot   = (__hip_bfloat16*)wot_f;
    __hip_bfloat16* wint  = (__hip_bfloat16*)wint_f;

    const dim3 blk(256);

    prep_kernel<<<1368, blk, 0, stream>>>(wd, gw, pw, wo, wb, wc, w_in, tab,
                                          cat0, cat1, gwt, pwt, wot, wint);
    gemm_in_kernel<<<dim3(4, 128), blk, 0, stream>>>(x, wint, b_in, h, ht);

    const dim3 qgrid(5, BLn / 64);
    const dim3 ggrid(4, BLn / 64);
    const dim3 sgrid(16, 16, BB);

    // ---- layer 0 (full sequence) ----
    lnconv_kernel<<<BLn / 32, blk, 0, stream>>>(h, ln_g, ln_b, conv_w, conv_b, xn_bf, xc_bf);
    gemm_core<0><<<qgrid, blk, 0, stream>>>((const short*)xc_bf, (const short*)cat0,
                                            bd, nullptr, nullptr, delta, Btm, Ctm, nullptr);
    ssm_chunk_kernel<0><<<sgrid, blk, 0, stream>>>(delta, Btm, nullptr, loglam,
                                                   sA, sB, nullptr);
    ssm_chunk_kernel<1><<<sgrid, blk, 0, stream>>>(delta, Btm, Ctm, loglam,
                                                   sA, sB, ys);
    gemm_sk_kernel<<<512, blk, 0, stream>>>(ys, wot, Pbuf);
    gemm_core<1><<<ggrid, blk, 0, stream>>>((const short*)xn_bf, (const short*)gwt,
                                            gb, Pbuf, bo, nullptr, nullptr, nullptr, xsg_bf);
    gemm_core<2><<<ggrid, blk, 0, stream>>>((const short*)xsg_bf, (const short*)pwt,
                                            pb, h, nullptr, xt1, nullptr, nullptr, nullptr);

    // ---- layer 1 (only final state needed downstream) ----
    lnconv_kernel<<<BLn / 32, blk, 0, stream>>>(xt1, ln_g + DD, ln_b + DD,
                                                conv_w + DD * 3, conv_b + DD, xn_bf, xc_bf);
    gemm_core<0><<<qgrid, blk, 0, stream>>>((const short*)xc_bf, (const short*)cat1,
                                            bd + DD, nullptr, nullptr, delta, Btm, Ctm, nullptr);
    ssm_chunk_kernel<0><<<sgrid, blk, 0, stream>>>(delta, Btm, nullptr, loglam + DD * NN,
                                                   sA, sB, nullptr);
    last_ssm_part_kernel<<<32, blk, 0, stream>>>(sA, sB, Ctm, wo + (size_t)DD * NN * DD, lpart);
    last_redproj_kernel<<<BB, blk, 0, stream>>>(lpart, bo + DD, xn_bf,
                                                gw + (size_t)DD * DD, gb + DD,
                                                pw + (size_t)DD * DD, pb + DD, xt1, xtlast);

    // ---- spectral path ----
    fft2_kernel<<<512, blk, 0, stream>>>(ht, tab, Xre, Xim);
    mag_part_kernel<<<dim3(5, 16), blk, 0, stream>>>(Xre, Xim, magp);
    topk_kernel<<<1, blk, 0, stream>>>(magp, sel);

    head_kernel<<<BB, blk, 0, stream>>>(Xre, Xim, sel, fr, fi, tab, xtlast,
                                        alpha, beta, gout, bout,
                                        hw1, hb1, hw2, hb2, (float*)d_out);
}

// Round 16
// 273.384 us; speedup vs baseline: 1.1144x; 1.1144x over previous
//
#include <hip/hip_runtime.h>
#include <hip/hip_bf16.h>
#include <math.h>

#define BB   4
#define LL   2048
#define INF_ 64
#define DD   256
#define NN   16
#define KK   32
#define BLn  (BB*LL)      // 8192
#define FCNT 1025
#define FSTR 1056
#define SKM  8192
#define SKN  256
#define PSZ  ((size_t)SKM * SKN)
#define IX(x) ((x) + ((x) >> 6))

typedef short short4v __attribute__((ext_vector_type(4)));
typedef short short8 __attribute__((ext_vector_type(8)));
typedef float f32x4  __attribute__((ext_vector_type(4)));

__device__ __forceinline__ float softplusf(float x) {
    return x > 20.f ? x : log1pf(__expf(x));
}
__device__ __forceinline__ float sigmoidf_(float x) {
    return 1.f / (1.f + __expf(-x));
}
__device__ __forceinline__ short bfs(float v) {
    __hip_bfloat16 h = __float2bfloat16(v);
    return *reinterpret_cast<short*>(&h);
}
// raw barrier: drain LDS ops only; global loads stay in flight
#define RAWBAR() do { asm volatile("s_waitcnt lgkmcnt(0)" ::: "memory"); \
                      __builtin_amdgcn_s_barrier(); } while (0)

// ============ fused prep: twiddle + all weight transpose/cast/pack ==========
__global__ void prep_kernel(const float* __restrict__ wd, const float* __restrict__ gw,
                            const float* __restrict__ pw, const float* __restrict__ wo,
                            const float* __restrict__ wb, const float* __restrict__ wc,
                            const float* __restrict__ w_in, float* __restrict__ tab,
                            __hip_bfloat16* __restrict__ cat0, __hip_bfloat16* __restrict__ cat1,
                            __hip_bfloat16* __restrict__ gwt, __hip_bfloat16* __restrict__ pwt,
                            __hip_bfloat16* __restrict__ wot, __hip_bfloat16* __restrict__ wint) {
    __shared__ float t[32][33];
    const int tid = threadIdx.x;
    int blk = blockIdx.x;
    if (blk < 8) {
        int i = blk * 256 + tid;
        if (i < 2048) {
            double ang = 2.0 * 3.14159265358979323846 * (double)i / 2048.0;
            tab[i]        = (float)cos(ang);
            tab[2048 + i] = (float)sin(ang);
        }
        return;
    }
    blk -= 8;
    const float* W; __hip_bfloat16* Wt; int K, N, bx, by;
    if (blk < 64)        { W = wd;                     Wt = cat0; K = 256;  N = 256; bx = blk & 7; by = blk >> 3; }
    else if (blk < 128)  { int q = blk - 64;  W = wd + 65536; Wt = cat1; K = 256; N = 256; bx = q & 7; by = q >> 3; }
    else if (blk < 192)  { int q = blk - 128; W = gw;  Wt = gwt;  K = 256;  N = 256; bx = q & 7; by = q >> 3; }
    else if (blk < 256)  { int q = blk - 192; W = pw;  Wt = pwt;  K = 256;  N = 256; bx = q & 7; by = q >> 3; }
    else if (blk < 1280) { int q = blk - 256; W = wo;  Wt = wot;  K = 4096; N = 256; bx = q & 7; by = q >> 3; }
    else if (blk < 1344) {
        int j = (blk - 1280) & 31;
        const float* src0 = (blk < 1312) ? wb : wb + DD * NN;
        const float* src1 = (blk < 1312) ? wc : wc + DD * NN;
        __hip_bfloat16* cat = (blk < 1312) ? cat0 : cat1;
        const float* src = (j < 16) ? src0 : src1;
        cat[(size_t)(256 + j) * 256 + tid] = __float2bfloat16(src[tid * 16 + (j & 15)]);
        return;
    } else { int q = blk - 1344; W = w_in; Wt = wint; K = 64; N = 256; bx = q & 7; by = q >> 3; }
    const int k0 = by * 32, n0 = bx * 32;
    if (k0 >= K) return;
    const int tx = tid & 31, ty = tid >> 5;
    for (int r = ty; r < 32; r += 8) t[r][tx] = W[(size_t)(k0 + r) * N + n0 + tx];
    __syncthreads();
    for (int r = ty; r < 32; r += 8)
        Wt[(size_t)(n0 + r) * K + k0 + tx] = __float2bfloat16(t[tx][r]);
}

// ============ input proj: h = x@w_in + b_in (MFMA), also writes ht ==========
__global__ __launch_bounds__(256)
void gemm_in_kernel(const float* __restrict__ x, const __hip_bfloat16* __restrict__ wint,
                    const float* __restrict__ b_in, float* __restrict__ h,
                    float* __restrict__ ht) {
    __shared__ alignas(16) short As[64][72];
    __shared__ alignas(16) short Bs[64][72];
    __shared__ float ts[64][68];
    const int tid = threadIdx.x;
    const int w = tid >> 6, lane = tid & 63;
    const int hi = lane >> 4, lo = lane & 15;
    const int row0 = blockIdx.y * 64, col0 = blockIdx.x * 64;
    const short* B = (const short*)wint;
#pragma unroll
    for (int e = 0; e < 4; ++e) {
        int q = e * 256 + tid;
        int r = q >> 4, c4 = (q & 15) * 4;
        float4 v = *(const float4*)&x[(size_t)(row0 + r) * 64 + c4];
        short4v s = {bfs(v.x), bfs(v.y), bfs(v.z), bfs(v.w)};
        *(short4v*)&As[r][c4] = s;
    }
#pragma unroll
    for (int e = 0; e < 2; ++e) {
        int q = e * 256 + tid;
        int r = q >> 3, c8 = (q & 7) * 8;
        *(short8*)&Bs[r][c8] = *(const short8*)&B[(size_t)(col0 + r) * 64 + c8];
    }
    __syncthreads();
    f32x4 acc[4];
    f32x4 zz = {0.f, 0.f, 0.f, 0.f};
#pragma unroll
    for (int n = 0; n < 4; ++n) acc[n] = zz;
#pragma unroll
    for (int s = 0; s < 2; ++s) {
        short8 af = *(const short8*)&As[w * 16 + lo][s * 32 + hi * 8];
#pragma unroll
        for (int n = 0; n < 4; ++n) {
            short8 bf = *(const short8*)&Bs[n * 16 + lo][s * 32 + hi * 8];
            acc[n] = __builtin_amdgcn_mfma_f32_16x16x32_bf16(af, bf, acc[n], 0, 0, 0);
        }
    }
#pragma unroll
    for (int n = 0; n < 4; ++n)
#pragma unroll
        for (int r = 0; r < 4; ++r) {
            const int row = row0 + w * 16 + hi * 4 + r;
            const int col = col0 + n * 16 + lo;
            float v = acc[n][r] + b_in[col];
            h[(size_t)row * 256 + col] = v;
            ts[n * 16 + lo][w * 16 + hi * 4 + r] = v;
        }
    __syncthreads();
    const int b = row0 >> 11, l0 = row0 & 2047, d0 = col0;
    const int dr = tid >> 2, seg = tid & 3;
    float* dst = ht + ((size_t)(b * 256 + d0 + dr)) * LL + l0 + seg * 16;
#pragma unroll
    for (int j = 0; j < 4; ++j)
        *(f32x4*)&dst[j * 4] = *(const f32x4*)&ts[dr][seg * 16 + j * 4];
}

// ============ fused LayerNorm + depthwise conv (32 rows/block) ==============
__global__ __launch_bounds__(256)
void lnconv_kernel(const float* __restrict__ X, const float* __restrict__ g,
                   const float* __restrict__ bln, const float* __restrict__ cw,
                   const float* __restrict__ cb, __hip_bfloat16* __restrict__ xn_bf,
                   __hip_bfloat16* __restrict__ xc_bf) {
    __shared__ float xs[34][260];
    const int tid = threadIdx.x;
    const int w = tid >> 6, lane = tid & 63;
    const int blk = blockIdx.x;
    const int b = (blk * 32) >> 11, L0 = (blk * 32) & 2047;
    const float4 g4 = *(const float4*)&g[lane * 4];
    const float4 b4 = *(const float4*)&bln[lane * 4];
    for (int slot = w; slot < 34; slot += 4) {
        const int l = L0 - 1 + slot;
        if (l < 0 || l >= LL) {
            f32x4 z = {0.f, 0.f, 0.f, 0.f};
            *(f32x4*)&xs[slot][lane * 4] = z;
            continue;
        }
        float4 v = *(const float4*)&X[((size_t)b * LL + l) * DD + lane * 4];
        float s = v.x + v.y + v.z + v.w;
#pragma unroll
        for (int off = 1; off < 64; off <<= 1) s += __shfl_xor(s, off);
        float m = s * (1.f / DD);
        float cx = v.x - m, cy = v.y - m, cz = v.z - m, cw_ = v.w - m;
        float q = cx * cx + cy * cy + cz * cz + cw_ * cw_;
#pragma unroll
        for (int off = 1; off < 64; off <<= 1) q += __shfl_xor(q, off);
        float inv = rsqrtf(q * (1.f / DD) + 1e-5f);
        f32x4 y;
        y[0] = cx * inv * g4.x + b4.x;
        y[1] = cy * inv * g4.y + b4.y;
        y[2] = cz * inv * g4.z + b4.z;
        y[3] = cw_ * inv * g4.w + b4.w;
        *(f32x4*)&xs[slot][lane * 4] = y;
        if (slot >= 1 && slot <= 32) {
            short4v s4 = {bfs(y[0]), bfs(y[1]), bfs(y[2]), bfs(y[3])};
            *(short4v*)&xn_bf[((size_t)b * LL + l) * DD + lane * 4] = s4;
        }
    }
    __syncthreads();
    const int d = tid;
    const float w0 = cw[d * 3 + 0], w1 = cw[d * 3 + 1], w2 = cw[d * 3 + 2], cbd = cb[d];
    float xm = xs[0][d], x0 = xs[1][d];
    for (int rw = 0; rw < 32; ++rw) {
        float xp = xs[rw + 2][d];
        xc_bf[((size_t)b * LL + L0 + rw) * DD + d] =
            __float2bfloat16(fmaf(w0, xm, fmaf(w1, x0, fmaf(w2, xp, cbd))));
        xm = x0; x0 = xp;
    }
}

// ============ 64x64 MFMA core, K=256, depth-2 reg pipeline (round-13) =======
template<int MODE>
__global__ __launch_bounds__(256)
void gemm_core(const short* __restrict__ A, const short* __restrict__ Bw,
               const float* __restrict__ bias, const float* __restrict__ x1,
               const float* __restrict__ x2, float* __restrict__ o0,
               float* __restrict__ o1, float* __restrict__ o2,
               __hip_bfloat16* __restrict__ ob) {
    __shared__ alignas(16) short As[2][64][40];
    __shared__ alignas(16) short Bs[2][64][40];
    const int tid = threadIdx.x;
    const int w = tid >> 6, lane = tid & 63;
    const int hi = lane >> 4, lo = lane & 15;
    const int row0 = blockIdx.y * 64, col0 = blockIdx.x * 64;
    f32x4 acc[4];
    f32x4 zz = {0.f, 0.f, 0.f, 0.f};
#pragma unroll
    for (int n = 0; n < 4; ++n) acc[n] = zz;
    const int sr = tid >> 2, sc = (tid & 3) * 8;
    const size_t aoff = (size_t)(row0 + sr) * 256 + sc;
    const size_t boff = (size_t)(col0 + sr) * 256 + sc;
    short8 a_s0, b_s0, a_s1, b_s1;
#define GC_LOAD0(t) { a_s0 = *(const short8*)&A[aoff + (t) * 32]; \
                      b_s0 = *(const short8*)&Bw[boff + (t) * 32]; }
#define GC_LOAD1(t) { a_s1 = *(const short8*)&A[aoff + (t) * 32]; \
                      b_s1 = *(const short8*)&Bw[boff + (t) * 32]; }
#define GC_WRITE0(buf) { *(short8*)&As[buf][sr][sc] = a_s0; *(short8*)&Bs[buf][sr][sc] = b_s0; }
#define GC_WRITE1(buf) { *(short8*)&As[buf][sr][sc] = a_s1; *(short8*)&Bs[buf][sr][sc] = b_s1; }
#define GC_COMPUTE(buf) { \
        short8 af = *(const short8*)&As[buf][w * 16 + lo][hi * 8]; \
        short8 bf0 = *(const short8*)&Bs[buf][0 * 16 + lo][hi * 8]; \
        short8 bf1 = *(const short8*)&Bs[buf][1 * 16 + lo][hi * 8]; \
        short8 bf2 = *(const short8*)&Bs[buf][2 * 16 + lo][hi * 8]; \
        short8 bf3 = *(const short8*)&Bs[buf][3 * 16 + lo][hi * 8]; \
        acc[0] = __builtin_amdgcn_mfma_f32_16x16x32_bf16(af, bf0, acc[0], 0, 0, 0); \
        acc[1] = __builtin_amdgcn_mfma_f32_16x16x32_bf16(af, bf1, acc[1], 0, 0, 0); \
        acc[2] = __builtin_amdgcn_mfma_f32_16x16x32_bf16(af, bf2, acc[2], 0, 0, 0); \
        acc[3] = __builtin_amdgcn_mfma_f32_16x16x32_bf16(af, bf3, acc[3], 0, 0, 0); }
    GC_LOAD0(0); GC_LOAD1(1);
    GC_WRITE0(0);
    RAWBAR();
#pragma unroll
    for (int j = 0; j < 8; j += 2) {
        if (j + 2 < 8) GC_LOAD0(j + 2);
        GC_WRITE1(1);
        GC_COMPUTE(0);
        RAWBAR();
        if (j + 3 < 8) GC_LOAD1(j + 3);
        if (j + 2 < 8) GC_WRITE0(0);
        GC_COMPUTE(1);
        RAWBAR();
    }
#pragma unroll
    for (int n = 0; n < 4; ++n) {
#pragma unroll
        for (int r = 0; r < 4; ++r) {
            const int row = row0 + w * 16 + hi * 4 + r;
            const int col = col0 + n * 16 + lo;
            float v = acc[n][r];
            if constexpr (MODE == 0) {
                if (col < 256)      o0[(size_t)row * 256 + col] = softplusf(v + bias[col]);
                else if (col < 272) o1[(size_t)row * 16 + col - 256] = v;
                else if (col < 288) o2[(size_t)row * 16 + col - 272] = v;
            } else if constexpr (MODE == 1) {
                float gv = sigmoidf_(v + bias[col]);
                size_t idx = (size_t)row * 256 + col;
                float s = x1[idx] + x1[PSZ + idx] + x1[2 * PSZ + idx] + x1[3 * PSZ + idx] + x2[col];
                ob[idx] = __float2bfloat16(gv * s);
            } else {
                o0[(size_t)row * 256 + col] = v + bias[col] + x1[(size_t)row * 256 + col];
            }
        }
    }
}

// ============ split-K GEMM ys@wo: block 128x128, waves 64x64, KSPLIT=4 ======
// 4m x 4n register tile halves LDS-read bytes per MFMA vs 2m x 4n.
__global__ __launch_bounds__(256)
void gemm_sk_kernel(const __hip_bfloat16* __restrict__ Abf, const __hip_bfloat16* __restrict__ Wt,
                    float* __restrict__ P) {
    __shared__ alignas(16) short As[2][128][40];
    __shared__ alignas(16) short Bs[2][128][40];
    const int tid = threadIdx.x;
    const int f = blockIdx.x;                   // 0..511
    const int xcd = f & 7, s = f >> 3;          // s 0..63
    const int colb = s & 1, kb = (s >> 1) & 3, u = s >> 3;  // u 0..7
    const int rowb = xcd + u * 8;               // 0..63 bijective
    const int row0 = rowb * 128, col0 = colb * 128;
    const size_t kbase = (size_t)kb * 1024;
    const int w = tid >> 6, lane = tid & 63;
    const int hi = lane >> 4, lo = lane & 15;
    const int mrow = (w >> 1) * 64, ncol = (w & 1) * 64;   // wave sub-tile
    const short* A = (const short*)Abf;
    const short* B = (const short*)Wt;
    f32x4 acc[4][4];
    f32x4 zz = {0.f, 0.f, 0.f, 0.f};
#pragma unroll
    for (int m = 0; m < 4; ++m)
#pragma unroll
        for (int n = 0; n < 4; ++n) acc[m][n] = zz;
    // staging: A 128x32 = 512 short8 chunks (2/thr); B 128x32 same
    const int r0 = tid >> 2,          c0 = (tid & 3) * 8;
    const int r1 = (256 + tid) >> 2,  c1 = ((256 + tid) & 3) * 8;
    const size_t ao0 = (size_t)(row0 + r0) * 4096 + kbase + c0;
    const size_t ao1 = (size_t)(row0 + r1) * 4096 + kbase + c1;
    const size_t bo0 = (size_t)(col0 + r0) * 4096 + kbase + c0;
    const size_t bo1 = (size_t)(col0 + r1) * 4096 + kbase + c1;
    short8 a0_s0, a1_s0, b0_s0, b1_s0, a0_s1, a1_s1, b0_s1, b1_s1;
#define SK_LOAD0(t) { size_t k0 = (size_t)(t) * 32; \
        a0_s0 = *(const short8*)&A[ao0 + k0]; a1_s0 = *(const short8*)&A[ao1 + k0]; \
        b0_s0 = *(const short8*)&B[bo0 + k0]; b1_s0 = *(const short8*)&B[bo1 + k0]; }
#define SK_LOAD1(t) { size_t k0 = (size_t)(t) * 32; \
        a0_s1 = *(const short8*)&A[ao0 + k0]; a1_s1 = *(const short8*)&A[ao1 + k0]; \
        b0_s1 = *(const short8*)&B[bo0 + k0]; b1_s1 = *(const short8*)&B[bo1 + k0]; }
#define SK_WRITE0(buf) { *(short8*)&As[buf][r0][c0] = a0_s0; *(short8*)&As[buf][r1][c1] = a1_s0; \
                         *(short8*)&Bs[buf][r0][c0] = b0_s0; *(short8*)&Bs[buf][r1][c1] = b1_s0; }
#define SK_WRITE1(buf) { *(short8*)&As[buf][r0][c0] = a0_s1; *(short8*)&As[buf][r1][c1] = a1_s1; \
                         *(short8*)&Bs[buf][r0][c0] = b0_s1; *(short8*)&Bs[buf][r1][c1] = b1_s1; }
#define MF(a_, b_, c_) __builtin_amdgcn_mfma_f32_16x16x32_bf16(a_, b_, c_, 0, 0, 0)
#define SK_COMPUTE(buf) { \
        short8 af0 = *(const short8*)&As[buf][mrow + 0 * 16 + lo][hi * 8]; \
        short8 af1 = *(const short8*)&As[buf][mrow + 1 * 16 + lo][hi * 8]; \
        short8 af2 = *(const short8*)&As[buf][mrow + 2 * 16 + lo][hi * 8]; \
        short8 af3 = *(const short8*)&As[buf][mrow + 3 * 16 + lo][hi * 8]; \
        short8 bf0 = *(const short8*)&Bs[buf][ncol + 0 * 16 + lo][hi * 8]; \
        short8 bf1 = *(const short8*)&Bs[buf][ncol + 1 * 16 + lo][hi * 8]; \
        short8 bf2 = *(const short8*)&Bs[buf][ncol + 2 * 16 + lo][hi * 8]; \
        short8 bf3 = *(const short8*)&Bs[buf][ncol + 3 * 16 + lo][hi * 8]; \
        acc[0][0]=MF(af0,bf0,acc[0][0]); acc[0][1]=MF(af0,bf1,acc[0][1]); \
        acc[0][2]=MF(af0,bf2,acc[0][2]); acc[0][3]=MF(af0,bf3,acc[0][3]); \
        acc[1][0]=MF(af1,bf0,acc[1][0]); acc[1][1]=MF(af1,bf1,acc[1][1]); \
        acc[1][2]=MF(af1,bf2,acc[1][2]); acc[1][3]=MF(af1,bf3,acc[1][3]); \
        acc[2][0]=MF(af2,bf0,acc[2][0]); acc[2][1]=MF(af2,bf1,acc[2][1]); \
        acc[2][2]=MF(af2,bf2,acc[2][2]); acc[2][3]=MF(af2,bf3,acc[2][3]); \
        acc[3][0]=MF(af3,bf0,acc[3][0]); acc[3][1]=MF(af3,bf1,acc[3][1]); \
        acc[3][2]=MF(af3,bf2,acc[3][2]); acc[3][3]=MF(af3,bf3,acc[3][3]); }
    SK_LOAD0(0); SK_LOAD1(1);
    SK_WRITE0(0);
    RAWBAR();
    for (int j = 0; j < 32; j += 2) {
        if (j + 2 < 32) SK_LOAD0(j + 2);
        SK_WRITE1(1);
        SK_COMPUTE(0);
        RAWBAR();
        if (j + 3 < 32) SK_LOAD1(j + 3);
        if (j + 2 < 32) SK_WRITE0(0);
        SK_COMPUTE(1);
        RAWBAR();
    }
    float* Pk = P + (size_t)kb * PSZ;
#pragma unroll
    for (int m = 0; m < 4; ++m)
#pragma unroll
        for (int n = 0; n < 4; ++n)
#pragma unroll
            for (int r = 0; r < 4; ++r) {
                int rr = row0 + mrow + m * 16 + hi * 4 + r;
                int cc = col0 + ncol + n * 16 + lo;
                Pk[(size_t)rr * SKN + cc] = acc[m][n][r];
            }
}

// ============ chunked SSM scan (PHASE 1 computes its own hstart) ============
template<int PHASE>
__global__ void ssm_chunk_kernel(const float* __restrict__ delta, const float* __restrict__ Bt,
                                 const float* __restrict__ Ct, const float* __restrict__ loglam,
                                 float* __restrict__ sA, float* __restrict__ sB,
                                 __hip_bfloat16* __restrict__ ys) {
    __shared__ float dl[128][16];
    __shared__ float btl[128][16];
    __shared__ float ctl[128][16];
    const int dblk = blockIdx.x, c = blockIdx.y, b = blockIdx.z;
    const int tid = threadIdx.x;
    const size_t lbase = (size_t)b * LL + c * 128;
    for (int i = tid; i < 2048; i += 256) {
        int l = i >> 4, q = i & 15;
        dl[l][q]  = delta[(lbase + l) * DD + dblk * 16 + q];
        btl[l][q] = Bt[(lbase + l) * NN + q];
        if (PHASE == 1) ctl[l][q] = Ct[(lbase + l) * NN + q];
    }
    float hv = 0.f, ap = 1.f;
    if (PHASE == 1) {
        for (int cc = 0; cc < c; ++cc) {
            size_t oi = ((size_t)(b * 16 + cc)) * 4096 + dblk * 256 + tid;
            hv = fmaf(sA[oi], hv, sB[oi]);
        }
    }
    __syncthreads();
    const int dloc = tid >> 4, n = tid & 15;
    const float lam = softplusf(loglam[(dblk * 16 + dloc) * NN + n]);
    for (int l = 0; l < 128; ++l) {
        float dv = dl[l][dloc];
        float a = __expf(-dv * lam);
        hv = fmaf(a, hv, dv * btl[l][n]);
        if (PHASE == 0) ap *= a;
        else ys[(lbase + l) * (DD * NN) + dblk * 256 + tid] = __float2bfloat16(hv * ctl[l][n]);
    }
    if (PHASE == 0) {
        size_t oi = ((size_t)(b * 16 + c)) * 4096 + dblk * 256 + tid;
        sA[oi] = ap; sB[oi] = hv;
    }
}

// ============ layer-2 last-position: chain hfin in-kernel, split-K part ====
__global__ void last_ssm_part_kernel(const float* __restrict__ sA, const float* __restrict__ sB,
                                     const float* __restrict__ Ct,
                                     const float* __restrict__ wo, float* __restrict__ part) {
    __shared__ float hC[4][128];
    const int c = blockIdx.x, tid = threadIdx.x;
    const int p0 = c * 128;
#pragma unroll
    for (int e = 0; e < 2; ++e) {
        int i = e * 256 + tid;
        int b = i >> 7, p = i & 127;
        float hh = 0.f;
#pragma unroll
        for (int cc = 0; cc < 16; ++cc) {
            size_t oi = ((size_t)(b * 16 + cc)) * 4096 + p0 + p;
            hh = fmaf(sA[oi], hh, sB[oi]);
        }
        hC[b][p] = hh * Ct[((size_t)b * LL + (LL - 1)) * NN + (p & 15)];
    }
    __syncthreads();
    float a0 = 0.f, a1 = 0.f, a2 = 0.f, a3 = 0.f;
    for (int p = 0; p < 128; ++p) {
        float wv = wo[(size_t)(p0 + p) * DD + tid];
        a0 = fmaf(hC[0][p], wv, a0);
        a1 = fmaf(hC[1][p], wv, a1);
        a2 = fmaf(hC[2][p], wv, a2);
        a3 = fmaf(hC[3][p], wv, a3);
    }
    part[(0 * 32 + c) * DD + tid] = a0;
    part[(1 * 32 + c) * DD + tid] = a1;
    part[(2 * 32 + c) * DD + tid] = a2;
    part[(3 * 32 + c) * DD + tid] = a3;
}

__global__ void last_redproj_kernel(const float* __restrict__ part, const float* __restrict__ bo,
                                    const __hip_bfloat16* __restrict__ xn, const float* __restrict__ gw,
                                    const float* __restrict__ gb, const float* __restrict__ pw,
                                    const float* __restrict__ pb, const float* __restrict__ resid,
                                    float* __restrict__ xtlast) {
    __shared__ float xrow[256];
    __shared__ float xsg[256];
    const int b = blockIdx.x, d = threadIdx.x;
    float ol = bo[d];
#pragma unroll
    for (int c = 0; c < 32; ++c) ol += part[(b * 32 + c) * DD + d];
    const size_t rbase = ((size_t)b * LL + (LL - 1)) * DD;
    xrow[d] = __bfloat162float(xn[rbase + d]);
    __syncthreads();
    float acc = gb[d];
    for (int k = 0; k < 256; ++k) acc = fmaf(xrow[k], gw[(size_t)k * DD + d], acc);
    xsg[d] = ol * sigmoidf_(acc);
    __syncthreads();
    float acc2 = pb[d];
    for (int k = 0; k < 256; ++k) acc2 = fmaf(xsg[k], pw[(size_t)k * DD + d], acc2);
    xtlast[b * DD + d] = acc2 + resid[rbase + d];
}

// ============ packed radix-2 FFT: 2 real seqs per block =====================
__global__ __launch_bounds__(256)
void fft2_kernel(const float* __restrict__ ht, const float* __restrict__ tab,
                 float* __restrict__ Xre, float* __restrict__ Xim) {
    __shared__ float re[2080];
    __shared__ float im[2080];
    __shared__ float c2[2048];
    __shared__ float s2[2048];
    const int tid = threadIdx.x;
    const int pair = blockIdx.x;
    const int b = pair >> 7, d0 = pair & 127;
    for (int p = tid; p < 2048; p += 256) {
        if (p >= 1) {
            int lh = 31 - __clz((unsigned)p);
            int j = p - (1 << lh);
            int t = j << (10 - lh);
            c2[p] = tab[t]; s2[p] = tab[2048 + t];
        }
    }
    const float* ha = ht + ((size_t)b * 256 + d0) * LL;
    const float* hb = ha + (size_t)128 * LL;
    for (int i = tid; i < 2048; i += 256) {
        int r = (int)(__brev((unsigned)i) >> 21);
        re[IX(r)] = ha[i];
        im[IX(r)] = hb[i];
    }
    __syncthreads();
#pragma unroll
    for (int s = 1; s <= 11; ++s) {
        const int half = 1 << (s - 1);
#pragma unroll
        for (int e = 0; e < 4; ++e) {
            int q = e * 256 + tid;
            int j = q & (half - 1);
            int i0 = ((q >> (s - 1)) << s) + j;
            int i1 = i0 + half;
            float wr = c2[half + j], wi = -s2[half + j];
            float xr = re[IX(i1)], xi = im[IX(i1)];
            float tr = xr * wr - xi * wi;
            float ti = xr * wi + xi * wr;
            float ur = re[IX(i0)], ui = im[IX(i0)];
            re[IX(i0)] = ur + tr; im[IX(i0)] = ui + ti;
            re[IX(i1)] = ur - tr; im[IX(i1)] = ui - ti;
        }
        __syncthreads();
    }
    const int seqa = b * 256 + d0;
    float* xra = Xre + (size_t)seqa * FSTR;
    float* xia = Xim + (size_t)seqa * FSTR;
    float* xrb = xra + (size_t)128 * FSTR;
    float* xib = xia + (size_t)128 * FSTR;
    for (int f = tid; f < FCNT; f += 256) {
        int nf = (2048 - f) & 2047;
        float zrf = re[IX(f)], zif = im[IX(f)];
        float zrn = re[IX(nf)], zin = im[IX(nf)];
        xra[f] = 0.5f * (zrf + zrn);
        xia[f] = 0.5f * (zif - zin);
        xrb[f] = 0.5f * (zif + zin);
        xib[f] = 0.5f * (zrn - zrf);
    }
}

// ============ mag partials / topk / fused xslast+head =======================
__global__ void mag_part_kernel(const float* __restrict__ Xre, const float* __restrict__ Xim,
                                float* __restrict__ part) {
    const int fb = blockIdx.x, sb = blockIdx.y;
    const int tid = threadIdx.x;
    const int f = fb * 256 + tid;
    float s = 0.f;
    if (f < FCNT) {
        for (int q = 0; q < 64; ++q) {
            size_t base = (size_t)(sb * 64 + q) * FSTR + f;
            float re = Xre[base], im = Xim[base];
            s += sqrtf(re * re + im * im);
        }
    }
    part[sb * 1280 + fb * 256 + tid] = s;
}

// top-32: 4 waves each do top-32 of a contiguous 320-slice, thread0 merges.
__global__ void topk_kernel(const float* __restrict__ part, int* __restrict__ sel) {
    __shared__ float vals[1280];
    __shared__ float wval[4][32];
    __shared__ int   widx[4][32];
    const int tid = threadIdx.x;
    const int lane = tid & 63, wid = tid >> 6;
    for (int i = tid; i < 1280; i += 256) {
        float v = -1e30f;
        if (i < FCNT) {
            v = 0.f;
#pragma unroll
            for (int sb = 0; sb < 16; ++sb) v += part[sb * 1280 + i];
        }
        vals[i] = v;
    }
    __syncthreads();
    const int base = wid * 320;
    for (int k = 0; k < 32; ++k) {
        float bv = -1e30f; int bi = 0x7fffffff;
#pragma unroll
        for (int q = 0; q < 5; ++q) {
            int i = base + q * 64 + lane;
            float v = vals[i];
            if (v > bv) { bv = v; bi = i; }
        }
#pragma unroll
        for (int off = 32; off > 0; off >>= 1) {
            float ov = __shfl_down(bv, off);
            int   oi = __shfl_down(bi, off);
            if (ov > bv || (ov == bv && oi < bi)) { bv = ov; bi = oi; }
        }
        bv = __shfl(bv, 0);
        bi = __shfl(bi, 0);
        if (lane == 0) { wval[wid][k] = bv; widx[wid][k] = bi; }
        vals[bi] = -1e30f;
    }
    __syncthreads();
    if (tid == 0) {
        int p0 = 0, p1 = 0, p2 = 0, p3 = 0;
        for (int k = 0; k < 32; ++k) {
            float v0 = wval[0][p0], v1 = wval[1][p1], v2 = wval[2][p2], v3 = wval[3][p3];
            int bw = 0; float bv = v0;
            if (v1 > bv) { bv = v1; bw = 1; }
            if (v2 > bv) { bv = v2; bw = 2; }
            if (v3 > bv) { bv = v3; bw = 3; }
            if (bw == 0)      { sel[k] = widx[0][p0++]; }
            else if (bw == 1) { sel[k] = widx[1][p1++]; }
            else if (bw == 2) { sel[k] = widx[2][p2++]; }
            else              { sel[k] = widx[3][p3++]; }
        }
    }
}

// fused: per-(b,d) spectral reconstruction at t=L-1, then mix/LN/MLP head
__global__ void head_kernel(const float* __restrict__ Xre, const float* __restrict__ Xim,
                            const int* __restrict__ sel, const float* __restrict__ fr,
                            const float* __restrict__ fi, const float* __restrict__ tab,
                            const float* __restrict__ xtlast,
                            const float* __restrict__ alpha, const float* __restrict__ beta,
                            const float* __restrict__ gout, const float* __restrict__ bout,
                            const float* __restrict__ hw1, const float* __restrict__ hb1,
                            const float* __restrict__ hw2, const float* __restrict__ hb2,
                            float* __restrict__ out) {
    __shared__ float red[256];
    __shared__ float z[256];
    __shared__ float hid[128];
    const int b = blockIdx.x, tid = threadIdx.x;
    const size_t sbase = (size_t)(b * 256 + tid) * FSTR;
    float xsl = 0.f;
    for (int j = 0; j < 32; ++j) {
        int f = sel[j];
        float xr = Xre[sbase + f];
        float xi = Xim[sbase + f];
        float frv = fr[tid * KK + j], fiv = fi[tid * KK + j];
        float xor_ = xr * frv - xi * fiv;
        float xoi  = xr * fiv + xi * frv;
        int kk2 = (f * (LL - 1)) & (LL - 1);
        float c = tab[kk2], s = tab[2048 + kk2];
        float w = (f == 0 || f == 1024) ? 1.f : 2.f;
        xsl = fmaf(w, xor_ * c - xoi * s, xsl);
    }
    xsl *= (1.f / LL);
    float zv = alpha[tid] * xtlast[b * 256 + tid] + beta[tid] * xsl;
    red[tid] = zv; __syncthreads();
    for (int s = 128; s > 0; s >>= 1) { if (tid < s) red[tid] += red[tid + s]; __syncthreads(); }
    float m = red[0] * (1.f / DD);
    __syncthreads();
    float c = zv - m;
    red[tid] = c * c; __syncthreads();
    for (int s = 128; s > 0; s >>= 1) { if (tid < s) red[tid] += red[tid + s]; __syncthreads(); }
    float var = red[0] * (1.f / DD);
    z[tid] = c * rsqrtf(var + 1e-5f) * gout[tid] + bout[tid];
    __syncthreads();
    if (tid < 128) {
        float a = hb1[tid];
        for (int k = 0; k < 256; ++k) a = fmaf(z[k], hw1[(size_t)k * 128 + tid], a);
        hid[tid] = a * sigmoidf_(a);
    }
    __syncthreads();
    if (tid < 2) {
        float a = hb2[tid];
        for (int k = 0; k < 128; ++k) a = fmaf(hid[k], hw2[(size_t)k * 2 + tid], a);
        out[b * 2 + tid] = a;
    }
}

extern "C" void kernel_launch(void* const* d_in, const int* in_sizes, int n_in,
                              void* d_out, int out_size, void* d_ws, size_t ws_size,
                              hipStream_t stream) {
    const float* x      = (const float*)d_in[0];
    const float* w_in   = (const float*)d_in[1];
    const float* b_in   = (const float*)d_in[2];
    const float* ln_g   = (const float*)d_in[3];
    const float* ln_b   = (const float*)d_in[4];
    const float* conv_w = (const float*)d_in[5];
    const float* conv_b = (const float*)d_in[6];
    const float* loglam = (const float*)d_in[7];
    const float* wd     = (const float*)d_in[8];
    const float* bd     = (const float*)d_in[9];
    const float* wb     = (const float*)d_in[10];
    const float* wc     = (const float*)d_in[11];
    const float* wo     = (const float*)d_in[12];
    const float* bo     = (const float*)d_in[13];
    const float* gw     = (const float*)d_in[14];
    const float* gb     = (const float*)d_in[15];
    const float* pw     = (const float*)d_in[16];
    const float* pb     = (const float*)d_in[17];
    const float* fr     = (const float*)d_in[18];
    const float* fi     = (const float*)d_in[19];
    const float* alpha  = (const float*)d_in[20];
    const float* beta   = (const float*)d_in[21];
    const float* gout   = (const float*)d_in[22];
    const float* bout   = (const float*)d_in[23];
    const float* hw1    = (const float*)d_in[24];
    const float* hb1    = (const float*)d_in[25];
    const float* hw2    = (const float*)d_in[26];
    const float* hb2    = (const float*)d_in[27];

    float* ws = (float*)d_ws;
    size_t o = 0;
    auto alloc = [&](size_t n) { float* p = ws + o; o += (n + 15) & ~(size_t)15; return p; };

    const size_t BLnDD = (size_t)BLn * DD;
    float* h      = alloc(BLnDD);
    float* xt1    = alloc(BLnDD);
    float* ht     = alloc(BLnDD);
    float* delta  = alloc(BLnDD);
    float* Pbuf   = alloc(4 * PSZ);                 // split-K partials (32 MB)
    float* Btm    = alloc((size_t)BLn * NN);
    float* Ctm    = alloc((size_t)BLn * NN);
    float* tab    = alloc(4096);
    float* ysf    = alloc(BLnDD * NN / 2);          // ys bf16; later Xre/Xim
    float* sA     = alloc((size_t)BB * 16 * 4096);
    float* sB     = alloc((size_t)BB * 16 * 4096);
    float* xnbf_f = alloc(BLnDD / 2);
    float* xcbf_f = alloc(BLnDD / 2);
    float* xsgf   = alloc(BLnDD / 2);
    float* cat0_f = alloc((size_t)320 * 256 / 2);
    float* cat1_f = alloc((size_t)320 * 256 / 2);
    float* gwt_f  = alloc((size_t)DD * DD / 2);
    float* pwt_f  = alloc((size_t)DD * DD / 2);
    float* wot_f  = alloc((size_t)DD * NN * DD / 2);
    float* wint_f = alloc((size_t)DD * 64 / 2);
    float* magp   = alloc(16 * 1280);
    int*   sel    = (int*)alloc(32);
    float* lpart  = alloc((size_t)BB * 32 * DD);
    float* xtlast = alloc(BB * DD);

    __hip_bfloat16* ys    = (__hip_bfloat16*)ysf;
    float*          Xre   = ysf;
    float*          Xim   = ysf + (size_t)1024 * FSTR;
    __hip_bfloat16* xn_bf = (__hip_bfloat16*)xnbf_f;
    __hip_bfloat16* xc_bf = (__hip_bfloat16*)xcbf_f;
    __hip_bfloat16* xsg_bf= (__hip_bfloat16*)xsgf;
    __hip_bfloat16* cat0  = (__hip_bfloat16*)cat0_f;
    __hip_bfloat16* cat1  = (__hip_bfloat16*)cat1_f;
    __hip_bfloat16* gwt   = (__hip_bfloat16*)gwt_f;
    __hip_bfloat16* pwt   = (__hip_bfloat16*)pwt_f;
    __hip_bfloat16* wot   = (__hip_bfloat16*)wot_f;
    __hip_bfloat16* wint  = (__hip_bfloat16*)wint_f;

    const dim3 blk(256);

    prep_kernel<<<1368, blk, 0, stream>>>(wd, gw, pw, wo, wb, wc, w_in, tab,
                                          cat0, cat1, gwt, pwt, wot, wint);
    gemm_in_kernel<<<dim3(4, 128), blk, 0, stream>>>(x, wint, b_in, h, ht);

    const dim3 qgrid(5, BLn / 64);
    const dim3 ggrid(4, BLn / 64);
    const dim3 sgrid(16, 16, BB);

    // ---- layer 0 (full sequence) ----
    lnconv_kernel<<<BLn / 32, blk, 0, stream>>>(h, ln_g, ln_b, conv_w, conv_b, xn_bf, xc_bf);
    gemm_core<0><<<qgrid, blk, 0, stream>>>((const short*)xc_bf, (const short*)cat0,
                                            bd, nullptr, nullptr, delta, Btm, Ctm, nullptr);
    ssm_chunk_kernel<0><<<sgrid, blk, 0, stream>>>(delta, Btm, nullptr, loglam,
                                                   sA, sB, nullptr);
    ssm_chunk_kernel<1><<<sgrid, blk, 0, stream>>>(delta, Btm, Ctm, loglam,
                                                   sA, sB, ys);
    gemm_sk_kernel<<<512, blk, 0, stream>>>(ys, wot, Pbuf);
    gemm_core<1><<<ggrid, blk, 0, stream>>>((const short*)xn_bf, (const short*)gwt,
                                            gb, Pbuf, bo, nullptr, nullptr, nullptr, xsg_bf);
    gemm_core<2><<<ggrid, blk, 0, stream>>>((const short*)xsg_bf, (const short*)pwt,
                                            pb, h, nullptr, xt1, nullptr, nullptr, nullptr);

    // ---- layer 1 (only final state needed downstream) ----
    lnconv_kernel<<<BLn / 32, blk, 0, stream>>>(xt1, ln_g + DD, ln_b + DD,
                                                conv_w + DD * 3, conv_b + DD, xn_bf, xc_bf);
    gemm_core<0><<<qgrid, blk, 0, stream>>>((const short*)xc_bf, (const short*)cat1,
                                            bd + DD, nullptr, nullptr, delta, Btm, Ctm, nullptr);
    ssm_chunk_kernel<0><<<sgrid, blk, 0, stream>>>(delta, Btm, nullptr, loglam + DD * NN,
                                                   sA, sB, nullptr);
    last_ssm_part_kernel<<<32, blk, 0, stream>>>(sA, sB, Ctm, wo + (size_t)DD * NN * DD, lpart);
    last_redproj_kernel<<<BB, blk, 0, stream>>>(lpart, bo + DD, xn_bf,
                                                gw + (size_t)DD * DD, gb + DD,
                                                pw + (size_t)DD * DD, pb + DD, xt1, xtlast);

    // ---- spectral path ----
    fft2_kernel<<<512, blk, 0, stream>>>(ht, tab, Xre, Xim);
    mag_part_kernel<<<dim3(5, 16), blk, 0, stream>>>(Xre, Xim, magp);
    topk_kernel<<<1, blk, 0, stream>>>(magp, sel);

    head_kernel<<<BB, blk, 0, stream>>>(Xre, Xim, sel, fr, fi, tab, xtlast,
                                        alpha, beta, gout, bout,
                                        hw1, hb1, hw2, hb2, (float*)d_out);
}